// Round 10
// baseline (134.254 us; speedup 1.0000x reference)
//
#include <hip/hip_runtime.h>
#include <hip/hip_bf16.h>
#include <cstdint>
#include <cstddef>

// Problem constants: B=16, S=2048, E=128, H=768, C=457
constexpr int Bn = 16, Sn = 2048, En = 128, Hn = 768, Cn = 457;
constexpr int NP = 512;                 // padded class dim for logits GEMM
using f32x4  = __attribute__((ext_vector_type(4))) float;
using bf16x8 = __attribute__((ext_vector_type(8))) short;

static __device__ inline unsigned short f2bf(float x) {
  __hip_bfloat16 b = __float2bfloat16(x);
  return *reinterpret_cast<unsigned short*>(&b);
}
static __device__ inline float bflo(unsigned int u) {  // low bf16 -> f32
  unsigned int v = u << 16;
  return *reinterpret_cast<float*>(&v);
}
static __device__ inline float bfhi(unsigned int u) {  // high bf16 -> f32
  unsigned int v = u & 0xFFFF0000u;
  return *reinterpret_cast<float*>(&v);
}

// ---------------------------------------------------------------------------
// Kernel 0: bit-pack entities_list, WORD-MAJOR: pk2[b][w][s], w = e>>5.
// 4096 waves x 8 tokens, unroll 8 (deep load pipeline).  [r8 exact]
// ---------------------------------------------------------------------------
__global__ __launch_bounds__(256) void pack_k(
    const int* __restrict__ el, unsigned int* __restrict__ pk2)
{
  const int l = threadIdx.x & 63;
  const int gw = blockIdx.x * 4 + (threadIdx.x >> 6);   // 4096 waves
  #pragma unroll 8
  for (int j = 0; j < 8; ++j) {
    const int tok = gw * 8 + j;                         // 0 .. 32767
    const int b = tok >> 11, s = tok & 2047;
    const int v0 = el[(size_t)tok * 128 + l];
    const int v1 = el[(size_t)tok * 128 + 64 + l];
    const unsigned long long b0 = __ballot(v0 != 0);
    const unsigned long long b1 = __ballot(v1 != 0);
    if (l == 0) {
      unsigned int* p = pk2 + (size_t)b * 4 * Sn + s;
      p[0]          = (unsigned int)b0;
      p[Sn]         = (unsigned int)(b0 >> 32);
      p[2 * Sn]     = (unsigned int)b1;
      p[3 * Sn]     = (unsigned int)(b1 >> 32);
    }
  }
}

// ---------------------------------------------------------------------------
// Kernel 1: pooling bmm, K-split by 4.  [r8 exact — measurement target]
// ---------------------------------------------------------------------------
constexpr int PBN = 64, PBK = 32, PLD = 40;   // Bs row stride 80B
constexpr int SCH = 4, SLEN = Sn / SCH, PNK = SLEN / PBK;   // 512-token slices
__global__ __launch_bounds__(512, 6) void pool_k(
    const float* __restrict__ hidden,       // (B,S,H)
    const unsigned int* __restrict__ pk2,   // (B,4,S) packed membership
    unsigned short* __restrict__ entp)      // (SCH, B*E, H) bf16 partials
{
  const int b = blockIdx.x, n0 = blockIdx.y * PBN, sc = blockIdx.z;
  const int s0 = sc * SLEN;
  const int tid = threadIdx.x, l = tid & 63, wv = tid >> 6;  // 8 waves
  const int wm = wv >> 2, wn = wv & 3;                       // 2 x 4

  __shared__ unsigned short Bs[2][PBN][PLD];  // 10.0 KB  (h x s)
  __shared__ unsigned int   PK2[4 * SLEN];    // 8 KB (word-major slice)

  // stage packed-bit slice: one uint4 per thread (coalesced per plane)
  {
    const int w = tid >> 7, off = (tid & 127) * 4;
    const uint4 v = *reinterpret_cast<const uint4*>(
        pk2 + (size_t)b * 4 * Sn + (size_t)w * Sn + s0 + off);
    *reinterpret_cast<uint4*>(&PK2[w * SLEN + off]) = v;
  }

  const float* hb = hidden + ((size_t)b * Sn + s0) * Hn + n0;

  auto loadh = [&](int kk, float (&f)[4]) {
    const int sb = kk * PBK + wv * 4;
    f[0] = hb[(size_t)(sb + 0) * Hn + l];
    f[1] = hb[(size_t)(sb + 1) * Hn + l];
    f[2] = hb[(size_t)(sb + 2) * Hn + l];
    f[3] = hb[(size_t)(sb + 3) * Hn + l];
  };

  auto stage_b = [&](int bsel, const float (&f)[4]) {
    uint2 dh;
    dh.x = (unsigned int)f2bf(f[0]) | ((unsigned int)f2bf(f[1]) << 16);
    dh.y = (unsigned int)f2bf(f[2]) | ((unsigned int)f2bf(f[3]) << 16);
    *reinterpret_cast<uint2*>(&Bs[bsel][l][wv * 4]) = dh;
  };

  f32x4 acc[4] = {};
  const int rl = l & 15, q = l >> 4, kr = q * 8;

  auto mfma_step = [&](int k, int cur) {
    const int sbase = k * PBK + kr;     // local s of this lane's 8-octet
    const bf16x8 bfr =
        *reinterpret_cast<const bf16x8*>(&Bs[cur][wn * 16 + rl][kr]);
    #pragma unroll
    for (int mp = 0; mp < 2; ++mp) {    // word shared by mi pair
      const int w = wm * 2 + mp;
      const uint4 u0 = *reinterpret_cast<const uint4*>(&PK2[w * SLEN + sbase]);
      const uint4 u1 = *reinterpret_cast<const uint4*>(&PK2[w * SLEN + sbase + 4]);
      #pragma unroll
      for (int mh = 0; mh < 2; ++mh) {  // mi = mp*2 + mh
        const int bi = mh * 16 + rl;
        bf16x8 afr;
        unsigned int* ap = reinterpret_cast<unsigned int*>(&afr);
        ap[0] = (((u0.x >> bi) & 1u) ? 0x3F80u : 0u) |
                (((u0.y >> bi) & 1u) ? 0x3F800000u : 0u);
        ap[1] = (((u0.z >> bi) & 1u) ? 0x3F80u : 0u) |
                (((u0.w >> bi) & 1u) ? 0x3F800000u : 0u);
        ap[2] = (((u1.x >> bi) & 1u) ? 0x3F80u : 0u) |
                (((u1.y >> bi) & 1u) ? 0x3F800000u : 0u);
        ap[3] = (((u1.z >> bi) & 1u) ? 0x3F80u : 0u) |
                (((u1.w >> bi) & 1u) ? 0x3F800000u : 0u);
        acc[mp * 2 + mh] = __builtin_amdgcn_mfma_f32_16x16x32_bf16(
            afr, bfr, acc[mp * 2 + mh], 0, 0, 0);
      }
    }
  };

  // prologue: prefetch hidden for steps 0,1; stage step 0
  float pf[3][4];
  loadh(0, pf[0]);
  loadh(1, pf[1]);
  __syncthreads();               // PK2 visible
  stage_b(0, pf[0]);
  __syncthreads();

  // fully-unrolled: load(k+2) early, mfma(k), stage(k+1), barrier
  #pragma unroll
  for (int k = 0; k < PNK; ++k) {
    if (k + 2 < PNK) loadh(k + 2, pf[(k + 2) % 3]);
    mfma_step(k, k & 1);
    if (k + 1 < PNK) stage_b((k + 1) & 1, pf[(k + 1) % 3]);
    __syncthreads();
  }

  // store bf16 partial tile (plain stores, own slice buffer)
  unsigned short* dst = entp + (size_t)sc * Bn * En * Hn;
  const int rg = q * 4;
  const int col = n0 + wn * 16 + rl;
  #pragma unroll
  for (int mi = 0; mi < 4; ++mi) {
    #pragma unroll
    for (int r = 0; r < 4; ++r) {
      const int e = wm * 64 + mi * 16 + rg + r;
      dst[(size_t)(b * En + e) * Hn + col] = f2bf(acc[mi][r]);
    }
  }
}

// ---------------------------------------------------------------------------
// Kernel 1b: finalize — sum 4 bf16 partials, /len, cast bf16.  [r8 exact]
// ---------------------------------------------------------------------------
__global__ __launch_bounds__(384) void finalize_k(
    const unsigned short* __restrict__ entp, const int* __restrict__ elen,
    unsigned short* __restrict__ entbf)
{
  const int be = blockIdx.x, t = threadIdx.x;      // 384 threads
  const float inv = 1.0f / (float)elen[be];
  constexpr size_t PSu = (size_t)Bn * En * Hn / 2; // plane stride in uints
  const unsigned int* src =
      reinterpret_cast<const unsigned int*>(entp) + (size_t)be * (Hn / 2) + t;
  float lo = 0.f, hi = 0.f;
  #pragma unroll
  for (int p = 0; p < SCH; ++p) {
    const unsigned int u = src[p * PSu];
    lo += bflo(u);
    hi += bfhi(u);
  }
  const unsigned int out = (unsigned int)f2bf(lo * inv) |
                           ((unsigned int)f2bf(hi * inv) << 16);
  reinterpret_cast<unsigned int*>(entbf)[(size_t)be * (Hn / 2) + t] = out;
}

// ---------------------------------------------------------------------------
// Kernel 2: cast W (457,768) f32 -> (512,768) bf16, zero-padding rows >= 457.
// ---------------------------------------------------------------------------
__global__ __launch_bounds__(256) void cast_w_k(
    const float* __restrict__ Wm, unsigned short* __restrict__ wbf)
{
  const int c = blockIdx.x;          // 0..511
  const int tid = threadIdx.x;
  unsigned short* dst = wbf + (size_t)c * Hn;
  if (c < Cn) {
    const float* src = Wm + (size_t)c * Hn;
    #pragma unroll
    for (int j = 0; j < 3; ++j) dst[tid + j * 256] = f2bf(src[tid + j * 256]);
  } else {
    #pragma unroll
    for (int j = 0; j < 3; ++j) dst[tid + j * 256] = 0;
  }
}

// ---------------------------------------------------------------------------
// Kernel 3: logits GEMM. C[2048][512] = A[2048][768] * B^T[512][768], bf16
// MFMA 16x16x32, fp32 accum. Tile 128x64, 4 waves (2x2), BK=32.  [r8 exact]
// ---------------------------------------------------------------------------
constexpr int BM = 128, BN = 64, BK = 32, LDP = BK + 24;   // 112B row stride
__global__ __launch_bounds__(256) void gemm_k(
    const unsigned short* __restrict__ A,   // (2048,768) bf16
    const unsigned short* __restrict__ Bm,  // (512,768) bf16 (B^T layout)
    float* __restrict__ Cm)                 // (2048,512) f32
{
  __shared__ unsigned short As[BM][LDP];
  __shared__ unsigned short Bs[BN][LDP];
  const int bm = blockIdx.x, bn = blockIdx.y;
  const int tid = threadIdx.x, lane = tid & 63, wv = tid >> 6;
  const int wm = wv >> 1, wn = wv & 1;          // 2x2 wave grid

  f32x4 acc[4][2] = {};

  for (int k0 = 0; k0 < Hn; k0 += BK) {
    #pragma unroll
    for (int i = 0; i < 2; ++i) {
      const int idx = tid + i * 256;
      const int r = idx >> 2, kc = (idx & 3) * 8;
      const unsigned short* src = A + (size_t)(bm * BM + r) * Hn + k0 + kc;
      *reinterpret_cast<ulonglong2*>(&As[r][kc]) =
          *reinterpret_cast<const ulonglong2*>(src);
    }
    {
      const int r = tid >> 2, kc = (tid & 3) * 8;
      const unsigned short* src = Bm + (size_t)(bn * BN + r) * Hn + k0 + kc;
      *reinterpret_cast<ulonglong2*>(&Bs[r][kc]) =
          *reinterpret_cast<const ulonglong2*>(src);
    }
    __syncthreads();

    const int kr = (lane >> 4) * 8, rl = lane & 15;
    bf16x8 af[4], bf[2];
    #pragma unroll
    for (int mi = 0; mi < 4; ++mi)
      af[mi] = *reinterpret_cast<const bf16x8*>(&As[wm * 64 + mi * 16 + rl][kr]);
    #pragma unroll
    for (int ni = 0; ni < 2; ++ni)
      bf[ni] = *reinterpret_cast<const bf16x8*>(&Bs[wn * 32 + ni * 16 + rl][kr]);
    #pragma unroll
    for (int mi = 0; mi < 4; ++mi)
      #pragma unroll
      for (int ni = 0; ni < 2; ++ni)
        acc[mi][ni] = __builtin_amdgcn_mfma_f32_16x16x32_bf16(
            af[mi], bf[ni], acc[mi][ni], 0, 0, 0);
    __syncthreads();
  }

  const int cl = lane & 15, rg = (lane >> 4) * 4;
  #pragma unroll
  for (int mi = 0; mi < 4; ++mi)
    #pragma unroll
    for (int ni = 0; ni < 2; ++ni) {
      const int col = bn * BN + wn * 32 + ni * 16 + cl;
      #pragma unroll
      for (int r = 0; r < 4; ++r) {
        const int row = bm * BM + wm * 64 + mi * 16 + rg + r;
        Cm[(size_t)row * NP + col] = acc[mi][ni][r];
      }
    }
}

// ---------------------------------------------------------------------------
// Kernel 4: CE per entity (one wave each; 4 waves/block). Bias added here.
// ---------------------------------------------------------------------------
__global__ __launch_bounds__(256) void ce_k(
    const float* __restrict__ logits,        // (2048,512)
    const float* __restrict__ bv,            // (457)
    const int* __restrict__ attr,            // (B,E)
    const unsigned char* __restrict__ emask, // (B,E)
    float* __restrict__ nll)                 // (2048)
{
  const int wv = threadIdx.x >> 6, lane = threadIdx.x & 63;
  const int be = blockIdx.x * 4 + wv;
  if (!emask[be]) { if (lane == 0) nll[be] = 0.f; return; }
  const float* row = logits + (size_t)be * NP;

  float mx = -3.4e38f;
  for (int i = lane; i < Cn; i += 64) mx = fmaxf(mx, row[i] + bv[i]);
  #pragma unroll
  for (int o = 32; o; o >>= 1) mx = fmaxf(mx, __shfl_xor(mx, o, 64));
  float sm = 0.f;
  for (int i = lane; i < Cn; i += 64) sm += __expf(row[i] + bv[i] - mx);
  #pragma unroll
  for (int o = 32; o; o >>= 1) sm += __shfl_xor(sm, o, 64);
  if (lane == 0) {
    const int tg = attr[be];
    nll[be] = mx + logf(sm) - (row[tg] + bv[tg]);
  }
}

// ---------------------------------------------------------------------------
// Kernel 5: deterministic final reduction.
// ---------------------------------------------------------------------------
__global__ __launch_bounds__(256) void reduce_k(
    const float* __restrict__ nll,
    const unsigned char* __restrict__ emask,
    float* __restrict__ out)
{
  const int tid = threadIdx.x;
  float s = 0.f, c = 0.f;
  for (int i = tid; i < Bn * En; i += 256) {
    s += nll[i];
    c += (float)emask[i];
  }
  #pragma unroll
  for (int o = 32; o; o >>= 1) {
    s += __shfl_xor(s, o, 64);
    c += __shfl_xor(c, o, 64);
  }
  __shared__ float ws_[4], wc_[4];
  const int wave = tid >> 6, lane = tid & 63;
  if (lane == 0) { ws_[wave] = s; wc_[wave] = c; }
  __syncthreads();
  if (tid == 0) {
    out[0] = (ws_[0] + ws_[1] + ws_[2] + ws_[3]) /
             (wc_[0] + wc_[1] + wc_[2] + wc_[3]);
  }
}

// ---------------------------------------------------------------------------
// MEASUREMENT ROUND: pool_k launched 4x (idempotent; deterministic stores of
// identical values). pool_time = (dur_us - 63.5)/3. Launches 2-4 run with
// hidden L3-warm: if pool is HBM-bound they run ~2x faster (delta small);
// if latency/VALU/barrier-bound, warm == cold (delta ~3x45).
// ---------------------------------------------------------------------------
extern "C" void kernel_launch(void* const* d_in, const int* in_sizes, int n_in,
                              void* d_out, int out_size, void* d_ws, size_t ws_size,
                              hipStream_t stream) {
  const float* hidden        = (const float*)d_in[0];
  const int* attr            = (const int*)d_in[3];
  const int* el              = (const int*)d_in[4];
  const int* elen            = (const int*)d_in[5];
  const unsigned char* emask = (const unsigned char*)d_in[6];
  const float* Wm            = (const float*)d_in[7];
  const float* bv            = (const float*)d_in[8];

  unsigned short* entbf = (unsigned short*)d_ws;            // 2048*768 bf16
  unsigned short* wbf   = entbf + (size_t)Bn * En * Hn;     // 512*768 bf16
  float* logits = (float*)(wbf + (size_t)NP * Hn);          // 2048*512 f32
  float* nll    = logits + (size_t)Bn * En * NP;            // 2048 f32
  unsigned int* pk2buf = (unsigned int*)(nll + Bn * En);    // B*4*S u32
  unsigned short* entp =
      (unsigned short*)(pk2buf + (size_t)Bn * 4 * Sn);      // SCH*2048*768 bf16

  hipLaunchKernelGGL(pack_k, dim3(1024), dim3(256), 0, stream, el, pk2buf);
  hipLaunchKernelGGL(pool_k, dim3(Bn, Hn / PBN, SCH), dim3(512), 0, stream,
                     hidden, pk2buf, entp);
  hipLaunchKernelGGL(pool_k, dim3(Bn, Hn / PBN, SCH), dim3(512), 0, stream,
                     hidden, pk2buf, entp);
  hipLaunchKernelGGL(pool_k, dim3(Bn, Hn / PBN, SCH), dim3(512), 0, stream,
                     hidden, pk2buf, entp);
  hipLaunchKernelGGL(pool_k, dim3(Bn, Hn / PBN, SCH), dim3(512), 0, stream,
                     hidden, pk2buf, entp);
  hipLaunchKernelGGL(finalize_k, dim3(Bn * En), dim3(384), 0, stream,
                     entp, elen, entbf);
  hipLaunchKernelGGL(cast_w_k, dim3(NP), dim3(256), 0, stream, Wm, wbf);
  hipLaunchKernelGGL(gemm_k, dim3(Bn * En / BM, NP / BN), dim3(256), 0, stream,
                     entbf, wbf, logits);
  hipLaunchKernelGGL(ce_k, dim3(Bn * En / 4), dim3(256), 0, stream,
                     logits, bv, attr, emask, nll);
  hipLaunchKernelGGL(reduce_k, dim3(1), dim3(256), 0, stream,
                     nll, emask, (float*)d_out);
}

// Round 11
// 64.463 us; speedup vs baseline: 2.0826x; 2.0826x over previous
//
#include <hip/hip_runtime.h>
#include <hip/hip_bf16.h>
#include <cstdint>
#include <cstddef>

// Problem constants: B=16, S=2048, E=128, H=768, C=457
constexpr int Bn = 16, Sn = 2048, En = 128, Hn = 768, Cn = 457;
constexpr int NP = 512;                 // padded class dim for logits GEMM
using f32x4  = __attribute__((ext_vector_type(4))) float;
using bf16x8 = __attribute__((ext_vector_type(8))) short;

static __device__ inline unsigned short f2bf(float x) {
  __hip_bfloat16 b = __float2bfloat16(x);
  return *reinterpret_cast<unsigned short*>(&b);
}
static __device__ inline float bflo(unsigned int u) {  // low bf16 -> f32
  unsigned int v = u << 16;
  return *reinterpret_cast<float*>(&v);
}
static __device__ inline float bfhi(unsigned int u) {  // high bf16 -> f32
  unsigned int v = u & 0xFFFF0000u;
  return *reinterpret_cast<float*>(&v);
}

// LDS-only barrier: waits ds ops, leaves global register-loads in flight.
// sched_barrier(0) on both sides per rule #18 (hipcc may hoist reg-only ops
// past inline-asm waitcnt despite "memory").
#define LGKM_BAR()                                            \
  do {                                                        \
    asm volatile("s_waitcnt lgkmcnt(0)" ::: "memory");        \
    __builtin_amdgcn_sched_barrier(0);                        \
    __builtin_amdgcn_s_barrier();                             \
    __builtin_amdgcn_sched_barrier(0);                        \
  } while (0)

// ---------------------------------------------------------------------------
// Kernel 0: bit-pack entities_list, WORD-MAJOR: pk2[b][w][s], w = e>>5.
// 4096 waves x 8 tokens, unroll 8.  [r8 exact]
// ---------------------------------------------------------------------------
__global__ __launch_bounds__(256) void pack_k(
    const int* __restrict__ el, unsigned int* __restrict__ pk2)
{
  const int l = threadIdx.x & 63;
  const int gw = blockIdx.x * 4 + (threadIdx.x >> 6);   // 4096 waves
  #pragma unroll 8
  for (int j = 0; j < 8; ++j) {
    const int tok = gw * 8 + j;                         // 0 .. 32767
    const int b = tok >> 11, s = tok & 2047;
    const int v0 = el[(size_t)tok * 128 + l];
    const int v1 = el[(size_t)tok * 128 + 64 + l];
    const unsigned long long b0 = __ballot(v0 != 0);
    const unsigned long long b1 = __ballot(v1 != 0);
    if (l == 0) {
      unsigned int* p = pk2 + (size_t)b * 4 * Sn + s;
      p[0]          = (unsigned int)b0;
      p[Sn]         = (unsigned int)(b0 >> 32);
      p[2 * Sn]     = (unsigned int)b1;
      p[3 * Sn]     = (unsigned int)(b1 >> 32);
    }
  }
}

// ---------------------------------------------------------------------------
// Kernel 1: pooling bmm, K-split by 4. PBK=64: 8 barrier-locked steps (was
// 16). lgkm-only barriers keep the depth-2 register prefetch in flight.
// A-fragments synthesized in registers from packed bits (as r8).
// ---------------------------------------------------------------------------
constexpr int PBN = 64, PBK2 = 64, PLD2 = 72;   // Bs row stride 144B
constexpr int SCH = 4, SLEN = Sn / SCH, PNK2 = SLEN / PBK2;   // 8 steps
__global__ __launch_bounds__(512, 6) void pool_k(
    const float* __restrict__ hidden,       // (B,S,H)
    const unsigned int* __restrict__ pk2,   // (B,4,S) packed membership
    unsigned short* __restrict__ entp)      // (SCH, B*E, H) bf16 partials
{
  const int b = blockIdx.x, n0 = blockIdx.y * PBN, sc = blockIdx.z;
  const int s0 = sc * SLEN;
  const int tid = threadIdx.x, l = tid & 63, wv = tid >> 6;  // 8 waves
  const int wm = wv >> 2, wn = wv & 3;                       // 2 x 4

  __shared__ unsigned short Bs[2][PBN][PLD2];  // 18.4 KB  (h x s)
  __shared__ unsigned int   PK2[4 * SLEN];     // 8 KB (word-major slice)

  // stage packed-bit slice: one uint4 per thread (coalesced per plane)
  {
    const int w = tid >> 7, off = (tid & 127) * 4;
    const uint4 v = *reinterpret_cast<const uint4*>(
        pk2 + (size_t)b * 4 * Sn + (size_t)w * Sn + s0 + off);
    *reinterpret_cast<uint4*>(&PK2[w * SLEN + off]) = v;
  }

  const float* hb = hidden + ((size_t)b * Sn + s0) * Hn + n0;

  auto loadh = [&](int kk, float (&f)[8]) {
    const int sb = kk * PBK2 + wv * 8;
    #pragma unroll
    for (int i = 0; i < 8; ++i)
      f[i] = hb[(size_t)(sb + i) * Hn + l];
  };

  auto stage_b = [&](int bsel, const float (&f)[8]) {
    uint2 d0, d1;
    d0.x = (unsigned int)f2bf(f[0]) | ((unsigned int)f2bf(f[1]) << 16);
    d0.y = (unsigned int)f2bf(f[2]) | ((unsigned int)f2bf(f[3]) << 16);
    d1.x = (unsigned int)f2bf(f[4]) | ((unsigned int)f2bf(f[5]) << 16);
    d1.y = (unsigned int)f2bf(f[6]) | ((unsigned int)f2bf(f[7]) << 16);
    *reinterpret_cast<uint2*>(&Bs[bsel][l][wv * 8])     = d0;
    *reinterpret_cast<uint2*>(&Bs[bsel][l][wv * 8 + 4]) = d1;
  };

  f32x4 acc[4] = {};
  const int rl = l & 15, q = l >> 4, kr = q * 8;

  auto mfma_step = [&](int k, int cur) {
    #pragma unroll
    for (int ks = 0; ks < 2; ++ks) {       // two 32-token sub-steps
      const int sbase = k * PBK2 + ks * 32 + kr;
      const bf16x8 bfr = *reinterpret_cast<const bf16x8*>(
          &Bs[cur][wn * 16 + rl][ks * 32 + kr]);
      #pragma unroll
      for (int mp = 0; mp < 2; ++mp) {     // word shared by mi pair
        const int w = wm * 2 + mp;
        const uint4 u0 = *reinterpret_cast<const uint4*>(&PK2[w * SLEN + sbase]);
        const uint4 u1 = *reinterpret_cast<const uint4*>(&PK2[w * SLEN + sbase + 4]);
        #pragma unroll
        for (int mh = 0; mh < 2; ++mh) {   // mi = mp*2 + mh
          const int bi = mh * 16 + rl;
          bf16x8 afr;
          unsigned int* ap = reinterpret_cast<unsigned int*>(&afr);
          ap[0] = (((u0.x >> bi) & 1u) ? 0x3F80u : 0u) |
                  (((u0.y >> bi) & 1u) ? 0x3F800000u : 0u);
          ap[1] = (((u0.z >> bi) & 1u) ? 0x3F80u : 0u) |
                  (((u0.w >> bi) & 1u) ? 0x3F800000u : 0u);
          ap[2] = (((u1.x >> bi) & 1u) ? 0x3F80u : 0u) |
                  (((u1.y >> bi) & 1u) ? 0x3F800000u : 0u);
          ap[3] = (((u1.z >> bi) & 1u) ? 0x3F80u : 0u) |
                  (((u1.w >> bi) & 1u) ? 0x3F800000u : 0u);
          acc[mp * 2 + mh] = __builtin_amdgcn_mfma_f32_16x16x32_bf16(
              afr, bfr, acc[mp * 2 + mh], 0, 0, 0);
        }
      }
    }
  };

  // prologue: prefetch hidden for steps 0,1; stage step 0
  float pf[3][8];
  loadh(0, pf[0]);
  loadh(1, pf[1]);
  LGKM_BAR();                    // PK2 visible (global loads stay in flight)
  stage_b(0, pf[0]);             // counted vmcnt wait on pf[0] only
  LGKM_BAR();

  // fully-unrolled: load(k+2) early, mfma(k), stage(k+1), lgkm barrier
  #pragma unroll
  for (int k = 0; k < PNK2; ++k) {
    if (k + 2 < PNK2) loadh(k + 2, pf[(k + 2) % 3]);
    mfma_step(k, k & 1);
    if (k + 1 < PNK2) {
      stage_b((k + 1) & 1, pf[(k + 1) % 3]);
      LGKM_BAR();
    }
  }

  // store bf16 partial tile (plain stores, own slice buffer)
  unsigned short* dst = entp + (size_t)sc * Bn * En * Hn;
  const int rg = q * 4;
  const int col = n0 + wn * 16 + rl;
  #pragma unroll
  for (int mi = 0; mi < 4; ++mi) {
    #pragma unroll
    for (int r = 0; r < 4; ++r) {
      const int e = wm * 64 + mi * 16 + rg + r;
      dst[(size_t)(b * En + e) * Hn + col] = f2bf(acc[mi][r]);
    }
  }
}

// ---------------------------------------------------------------------------
// Kernel 1b: finalize — sum 4 bf16 partials, /len, cast bf16.  [r8 exact]
// ---------------------------------------------------------------------------
__global__ __launch_bounds__(384) void finalize_k(
    const unsigned short* __restrict__ entp, const int* __restrict__ elen,
    unsigned short* __restrict__ entbf)
{
  const int be = blockIdx.x, t = threadIdx.x;      // 384 threads
  const float inv = 1.0f / (float)elen[be];
  constexpr size_t PSu = (size_t)Bn * En * Hn / 2; // plane stride in uints
  const unsigned int* src =
      reinterpret_cast<const unsigned int*>(entp) + (size_t)be * (Hn / 2) + t;
  float lo = 0.f, hi = 0.f;
  #pragma unroll
  for (int p = 0; p < SCH; ++p) {
    const unsigned int u = src[p * PSu];
    lo += bflo(u);
    hi += bfhi(u);
  }
  const unsigned int out = (unsigned int)f2bf(lo * inv) |
                           ((unsigned int)f2bf(hi * inv) << 16);
  reinterpret_cast<unsigned int*>(entbf)[(size_t)be * (Hn / 2) + t] = out;
}

// ---------------------------------------------------------------------------
// Kernel 2: cast W (457,768) f32 -> (512,768) bf16, zero-padding rows >= 457.
// ---------------------------------------------------------------------------
__global__ __launch_bounds__(256) void cast_w_k(
    const float* __restrict__ Wm, unsigned short* __restrict__ wbf)
{
  const int c = blockIdx.x;          // 0..511
  const int tid = threadIdx.x;
  unsigned short* dst = wbf + (size_t)c * Hn;
  if (c < Cn) {
    const float* src = Wm + (size_t)c * Hn;
    #pragma unroll
    for (int j = 0; j < 3; ++j) dst[tid + j * 256] = f2bf(src[tid + j * 256]);
  } else {
    #pragma unroll
    for (int j = 0; j < 3; ++j) dst[tid + j * 256] = 0;
  }
}

// ---------------------------------------------------------------------------
// Kernel 3: logits GEMM, retiled 64x32 -> 512 blocks (2/CU, was 0.5/CU).
// C[2048][512] = A[2048][768] * B^T[512][768], bf16 MFMA 16x16x32, fp32 acc.
// 4 waves (2x2), BK=32. Same K accumulation order as r8 (bit-identical).
// ---------------------------------------------------------------------------
constexpr int BM = 64, BN = 32, BK = 32, LDP = BK + 24;   // 112B row stride
__global__ __launch_bounds__(256) void gemm_k(
    const unsigned short* __restrict__ A,   // (2048,768) bf16
    const unsigned short* __restrict__ Bm,  // (512,768) bf16 (B^T layout)
    float* __restrict__ Cm)                 // (2048,512) f32
{
  __shared__ unsigned short As[BM][LDP];
  __shared__ unsigned short Bs[BN][LDP];
  const int bm = blockIdx.x, bn = blockIdx.y;
  const int tid = threadIdx.x, lane = tid & 63, wv = tid >> 6;
  const int wm = wv >> 1, wn = wv & 1;          // 2x2 wave grid

  f32x4 acc[2] = {};

  for (int k0 = 0; k0 < Hn; k0 += BK) {
    // stage A: 64 rows x 32 k = 256 chunks of 8 bf16; 1 per thread
    {
      const int r = tid >> 2, kc = (tid & 3) * 8;
      const unsigned short* src = A + (size_t)(bm * BM + r) * Hn + k0 + kc;
      *reinterpret_cast<ulonglong2*>(&As[r][kc]) =
          *reinterpret_cast<const ulonglong2*>(src);
    }
    // stage B: 32 rows x 32 k = 128 chunks; threads 0..127
    if (tid < 128) {
      const int r = tid >> 2, kc = (tid & 3) * 8;
      const unsigned short* src = Bm + (size_t)(bn * BN + r) * Hn + k0 + kc;
      *reinterpret_cast<ulonglong2*>(&Bs[r][kc]) =
          *reinterpret_cast<const ulonglong2*>(src);
    }
    __syncthreads();

    const int kr = (lane >> 4) * 8, rl = lane & 15;
    const bf16x8 bf = *reinterpret_cast<const bf16x8*>(&Bs[wn * 16 + rl][kr]);
    #pragma unroll
    for (int mi = 0; mi < 2; ++mi) {
      const bf16x8 af =
          *reinterpret_cast<const bf16x8*>(&As[wm * 32 + mi * 16 + rl][kr]);
      acc[mi] = __builtin_amdgcn_mfma_f32_16x16x32_bf16(af, bf, acc[mi], 0, 0, 0);
    }
    __syncthreads();
  }

  const int cl = lane & 15, rg = (lane >> 4) * 4;
  const int col = bn * BN + wn * 16 + cl;
  #pragma unroll
  for (int mi = 0; mi < 2; ++mi) {
    #pragma unroll
    for (int r = 0; r < 4; ++r) {
      const int row = bm * BM + wm * 32 + mi * 16 + rg + r;
      Cm[(size_t)row * NP + col] = acc[mi][r];
    }
  }
}

// ---------------------------------------------------------------------------
// Kernel 4: CE per entity (one wave each; 4 waves/block). Bias added here.
// ---------------------------------------------------------------------------
__global__ __launch_bounds__(256) void ce_k(
    const float* __restrict__ logits,        // (2048,512)
    const float* __restrict__ bv,            // (457)
    const int* __restrict__ attr,            // (B,E)
    const unsigned char* __restrict__ emask, // (B,E)
    float* __restrict__ nll)                 // (2048)
{
  const int wv = threadIdx.x >> 6, lane = threadIdx.x & 63;
  const int be = blockIdx.x * 4 + wv;
  if (!emask[be]) { if (lane == 0) nll[be] = 0.f; return; }
  const float* row = logits + (size_t)be * NP;

  float mx = -3.4e38f;
  for (int i = lane; i < Cn; i += 64) mx = fmaxf(mx, row[i] + bv[i]);
  #pragma unroll
  for (int o = 32; o; o >>= 1) mx = fmaxf(mx, __shfl_xor(mx, o, 64));
  float sm = 0.f;
  for (int i = lane; i < Cn; i += 64) sm += __expf(row[i] + bv[i] - mx);
  #pragma unroll
  for (int o = 32; o; o >>= 1) sm += __shfl_xor(sm, o, 64);
  if (lane == 0) {
    const int tg = attr[be];
    nll[be] = mx + logf(sm) - (row[tg] + bv[tg]);
  }
}

// ---------------------------------------------------------------------------
// Kernel 5: deterministic final reduction.
// ---------------------------------------------------------------------------
__global__ __launch_bounds__(256) void reduce_k(
    const float* __restrict__ nll,
    const unsigned char* __restrict__ emask,
    float* __restrict__ out)
{
  const int tid = threadIdx.x;
  float s = 0.f, c = 0.f;
  for (int i = tid; i < Bn * En; i += 256) {
    s += nll[i];
    c += (float)emask[i];
  }
  #pragma unroll
  for (int o = 32; o; o >>= 1) {
    s += __shfl_xor(s, o, 64);
    c += __shfl_xor(c, o, 64);
  }
  __shared__ float ws_[4], wc_[4];
  const int wave = tid >> 6, lane = tid & 63;
  if (lane == 0) { ws_[wave] = s; wc_[wave] = c; }
  __syncthreads();
  if (tid == 0) {
    out[0] = (ws_[0] + ws_[1] + ws_[2] + ws_[3]) /
             (wc_[0] + wc_[1] + wc_[2] + wc_[3]);
  }
}

// ---------------------------------------------------------------------------
extern "C" void kernel_launch(void* const* d_in, const int* in_sizes, int n_in,
                              void* d_out, int out_size, void* d_ws, size_t ws_size,
                              hipStream_t stream) {
  const float* hidden        = (const float*)d_in[0];
  const int* attr            = (const int*)d_in[3];
  const int* el              = (const int*)d_in[4];
  const int* elen            = (const int*)d_in[5];
  const unsigned char* emask = (const unsigned char*)d_in[6];
  const float* Wm            = (const float*)d_in[7];
  const float* bv            = (const float*)d_in[8];

  unsigned short* entbf = (unsigned short*)d_ws;            // 2048*768 bf16
  unsigned short* wbf   = entbf + (size_t)Bn * En * Hn;     // 512*768 bf16
  float* logits = (float*)(wbf + (size_t)NP * Hn);          // 2048*512 f32
  float* nll    = logits + (size_t)Bn * En * NP;            // 2048 f32
  unsigned int* pk2buf = (unsigned int*)(nll + Bn * En);    // B*4*S u32
  unsigned short* entp =
      (unsigned short*)(pk2buf + (size_t)Bn * 4 * Sn);      // SCH*2048*768 bf16

  hipLaunchKernelGGL(pack_k, dim3(1024), dim3(256), 0, stream, el, pk2buf);
  hipLaunchKernelGGL(pool_k, dim3(Bn, Hn / PBN, SCH), dim3(512), 0, stream,
                     hidden, pk2buf, entp);
  hipLaunchKernelGGL(finalize_k, dim3(Bn * En), dim3(384), 0, stream,
                     entp, elen, entbf);
  hipLaunchKernelGGL(cast_w_k, dim3(NP), dim3(256), 0, stream, Wm, wbf);
  hipLaunchKernelGGL(gemm_k, dim3(Bn * En / BM, NP / BN), dim3(256), 0, stream,
                     entbf, wbf, logits);
  hipLaunchKernelGGL(ce_k, dim3(Bn * En / 4), dim3(256), 0, stream,
                     logits, bv, attr, emask, nll);
  hipLaunchKernelGGL(reduce_k, dim3(1), dim3(256), 0, stream,
                     nll, emask, (float*)d_out);
}

// Round 12
// 62.291 us; speedup vs baseline: 2.1553x; 1.0349x over previous
//
#include <hip/hip_runtime.h>
#include <hip/hip_bf16.h>
#include <cstdint>
#include <cstddef>

// Problem constants: B=16, S=2048, E=128, H=768, C=457
constexpr int Bn = 16, Sn = 2048, En = 128, Hn = 768, Cn = 457;
constexpr int NP = 512;                 // padded class dim for logits GEMM
using f32x4  = __attribute__((ext_vector_type(4))) float;
using bf16x8 = __attribute__((ext_vector_type(8))) short;

static __device__ inline unsigned short f2bf(float x) {
  __hip_bfloat16 b = __float2bfloat16(x);
  return *reinterpret_cast<unsigned short*>(&b);
}
static __device__ inline float bflo(unsigned int u) {  // low bf16 -> f32
  unsigned int v = u << 16;
  return *reinterpret_cast<float*>(&v);
}
static __device__ inline float bfhi(unsigned int u) {  // high bf16 -> f32
  unsigned int v = u & 0xFFFF0000u;
  return *reinterpret_cast<float*>(&v);
}

// LDS-only barrier (rule #18 fencing).
#define LGKM_BAR()                                            \
  do {                                                        \
    asm volatile("s_waitcnt lgkmcnt(0)" ::: "memory");        \
    __builtin_amdgcn_sched_barrier(0);                        \
    __builtin_amdgcn_s_barrier();                             \
    __builtin_amdgcn_sched_barrier(0);                        \
  } while (0)

// ---------------------------------------------------------------------------
// Kernel 0: bit-pack entities_list, WORD-MAJOR: pk2[b][w][s], w = e>>5.
// 4096 waves x 8 tokens, unroll 8.  [r8 exact]
// ---------------------------------------------------------------------------
__global__ __launch_bounds__(256) void pack_k(
    const int* __restrict__ el, unsigned int* __restrict__ pk2)
{
  const int l = threadIdx.x & 63;
  const int gw = blockIdx.x * 4 + (threadIdx.x >> 6);   // 4096 waves
  #pragma unroll 8
  for (int j = 0; j < 8; ++j) {
    const int tok = gw * 8 + j;                         // 0 .. 32767
    const int b = tok >> 11, s = tok & 2047;
    const int v0 = el[(size_t)tok * 128 + l];
    const int v1 = el[(size_t)tok * 128 + 64 + l];
    const unsigned long long b0 = __ballot(v0 != 0);
    const unsigned long long b1 = __ballot(v1 != 0);
    if (l == 0) {
      unsigned int* p = pk2 + (size_t)b * 4 * Sn + s;
      p[0]          = (unsigned int)b0;
      p[Sn]         = (unsigned int)(b0 >> 32);
      p[2 * Sn]     = (unsigned int)b1;
      p[3 * Sn]     = (unsigned int)(b1 >> 32);
    }
  }
}

// ---------------------------------------------------------------------------
// Kernel 1: pooling bmm. OCCUPANCY 2x: PBN=32, 256 threads (4 waves 2x2),
// grid 16x24x4 = 1536 blocks = 6 blocks/CU (was 3). Same instruction mix as
// r11: in-register A-synth from packed bits, PBK=64, lgkm-only barriers,
// depth-2 register prefetch. Partials bf16 per slice.
// ---------------------------------------------------------------------------
constexpr int PBN = 32, PBK2 = 64, PLD2 = 72;   // Bs row stride 144B
constexpr int SCH = 4, SLEN = Sn / SCH, PNK2 = SLEN / PBK2;   // 8 steps
__global__ __launch_bounds__(256, 6) void pool_k(
    const float* __restrict__ hidden,       // (B,S,H)
    const unsigned int* __restrict__ pk2,   // (B,4,S) packed membership
    unsigned short* __restrict__ entp)      // (SCH, B*E, H) bf16 partials
{
  const int b = blockIdx.x, n0 = blockIdx.y * PBN, sc = blockIdx.z;
  const int s0 = sc * SLEN;
  const int tid = threadIdx.x, l = tid & 63, wv = tid >> 6;  // 4 waves
  const int wm = wv >> 1, wn = wv & 1;                       // 2 x 2

  __shared__ unsigned short Bs[2][PBN][PLD2];  // 9.2 KB  (h x s)
  __shared__ unsigned int   PK2[4 * SLEN];     // 8 KB (word-major slice)

  // stage packed-bit slice: 2048 uints / 256 thr = 8 each (2x uint4)
  {
    const int w = tid >> 6, off = (tid & 63) * 8;
    const unsigned int* srcp =
        pk2 + (size_t)b * 4 * Sn + (size_t)w * Sn + s0 + off;
    *reinterpret_cast<uint4*>(&PK2[w * SLEN + off]) =
        *reinterpret_cast<const uint4*>(srcp);
    *reinterpret_cast<uint4*>(&PK2[w * SLEN + off + 4]) =
        *reinterpret_cast<const uint4*>(srcp + 4);
  }

  const float* hb = hidden + ((size_t)b * Sn + s0) * Hn + n0;
  const int g = wv * 2 + (l >> 5), col = l & 31;   // 8 token-groups x 32 cols

  auto loadh = [&](int kk, float (&f)[8]) {
    const int sb = kk * PBK2 + g * 8;
    #pragma unroll
    for (int i = 0; i < 8; ++i)
      f[i] = hb[(size_t)(sb + i) * Hn + col];
  };

  auto stage_b = [&](int bsel, const float (&f)[8]) {
    uint2 d0, d1;
    d0.x = (unsigned int)f2bf(f[0]) | ((unsigned int)f2bf(f[1]) << 16);
    d0.y = (unsigned int)f2bf(f[2]) | ((unsigned int)f2bf(f[3]) << 16);
    d1.x = (unsigned int)f2bf(f[4]) | ((unsigned int)f2bf(f[5]) << 16);
    d1.y = (unsigned int)f2bf(f[6]) | ((unsigned int)f2bf(f[7]) << 16);
    *reinterpret_cast<uint2*>(&Bs[bsel][col][g * 8])     = d0;
    *reinterpret_cast<uint2*>(&Bs[bsel][col][g * 8 + 4]) = d1;
  };

  f32x4 acc[4] = {};
  const int rl = l & 15, q = l >> 4, kr = q * 8;

  auto mfma_step = [&](int k, int cur) {
    #pragma unroll
    for (int ks = 0; ks < 2; ++ks) {       // two 32-token sub-steps
      const int sbase = k * PBK2 + ks * 32 + kr;
      const bf16x8 bfr = *reinterpret_cast<const bf16x8*>(
          &Bs[cur][wn * 16 + rl][ks * 32 + kr]);
      #pragma unroll
      for (int mp = 0; mp < 2; ++mp) {     // word shared by mi pair
        const int w = wm * 2 + mp;
        const uint4 u0 = *reinterpret_cast<const uint4*>(&PK2[w * SLEN + sbase]);
        const uint4 u1 = *reinterpret_cast<const uint4*>(&PK2[w * SLEN + sbase + 4]);
        #pragma unroll
        for (int mh = 0; mh < 2; ++mh) {   // mi = mp*2 + mh
          const int bi = mh * 16 + rl;
          bf16x8 afr;
          unsigned int* ap = reinterpret_cast<unsigned int*>(&afr);
          ap[0] = (((u0.x >> bi) & 1u) ? 0x3F80u : 0u) |
                  (((u0.y >> bi) & 1u) ? 0x3F800000u : 0u);
          ap[1] = (((u0.z >> bi) & 1u) ? 0x3F80u : 0u) |
                  (((u0.w >> bi) & 1u) ? 0x3F800000u : 0u);
          ap[2] = (((u1.x >> bi) & 1u) ? 0x3F80u : 0u) |
                  (((u1.y >> bi) & 1u) ? 0x3F800000u : 0u);
          ap[3] = (((u1.z >> bi) & 1u) ? 0x3F80u : 0u) |
                  (((u1.w >> bi) & 1u) ? 0x3F800000u : 0u);
          acc[mp * 2 + mh] = __builtin_amdgcn_mfma_f32_16x16x32_bf16(
              afr, bfr, acc[mp * 2 + mh], 0, 0, 0);
        }
      }
    }
  };

  // prologue: prefetch hidden for steps 0,1; stage step 0
  float pf[3][8];
  loadh(0, pf[0]);
  loadh(1, pf[1]);
  LGKM_BAR();                    // PK2 visible (global loads stay in flight)
  stage_b(0, pf[0]);
  LGKM_BAR();

  // fully-unrolled: load(k+2) early, mfma(k), stage(k+1), lgkm barrier
  #pragma unroll
  for (int k = 0; k < PNK2; ++k) {
    if (k + 2 < PNK2) loadh(k + 2, pf[(k + 2) % 3]);
    mfma_step(k, k & 1);
    if (k + 1 < PNK2) {
      stage_b((k + 1) & 1, pf[(k + 1) % 3]);
      LGKM_BAR();
    }
  }

  // store bf16 partial tile (plain stores, own slice buffer)
  unsigned short* dst = entp + (size_t)sc * Bn * En * Hn;
  const int rg = q * 4;
  const int colo = n0 + wn * 16 + rl;
  #pragma unroll
  for (int mi = 0; mi < 4; ++mi) {
    #pragma unroll
    for (int r = 0; r < 4; ++r) {
      const int e = wm * 64 + mi * 16 + rg + r;
      dst[(size_t)(b * En + e) * Hn + colo] = f2bf(acc[mi][r]);
    }
  }
}

// ---------------------------------------------------------------------------
// Kernel 1b: fused finalize + W-cast (one launch, branch on blockIdx).
// Blocks [0, 2048): sum 4 bf16 partials, /len, cast bf16.
// Blocks [2048, 2560): cast W row (c = blk - 2048) f32 -> bf16, pad >= 457.
// ---------------------------------------------------------------------------
__global__ __launch_bounds__(384) void fincast_k(
    const unsigned short* __restrict__ entp, const int* __restrict__ elen,
    const float* __restrict__ Wm,
    unsigned short* __restrict__ entbf, unsigned short* __restrict__ wbf)
{
  const int blk = blockIdx.x, t = threadIdx.x;     // 384 threads
  if (blk < Bn * En) {
    const int be = blk;
    const float inv = 1.0f / (float)elen[be];
    constexpr size_t PSu = (size_t)Bn * En * Hn / 2;
    const unsigned int* src =
        reinterpret_cast<const unsigned int*>(entp) + (size_t)be * (Hn / 2) + t;
    float lo = 0.f, hi = 0.f;
    #pragma unroll
    for (int p = 0; p < SCH; ++p) {
      const unsigned int u = src[p * PSu];
      lo += bflo(u);
      hi += bfhi(u);
    }
    const unsigned int out = (unsigned int)f2bf(lo * inv) |
                             ((unsigned int)f2bf(hi * inv) << 16);
    reinterpret_cast<unsigned int*>(entbf)[(size_t)be * (Hn / 2) + t] = out;
  } else {
    const int c = blk - Bn * En;                   // 0..511
    unsigned int out = 0u;
    if (c < Cn) {
      const float* wp = Wm + (size_t)c * Hn + 2 * t;
      out = (unsigned int)f2bf(wp[0]) | ((unsigned int)f2bf(wp[1]) << 16);
    }
    reinterpret_cast<unsigned int*>(wbf)[(size_t)c * (Hn / 2) + t] = out;
  }
}

// ---------------------------------------------------------------------------
// Kernel 2: logits GEMM, 64x32 tiles, 512 blocks (2/CU).  [r11 exact]
// ---------------------------------------------------------------------------
constexpr int BM = 64, BN = 32, BK = 32, LDP = BK + 24;   // 112B row stride
__global__ __launch_bounds__(256) void gemm_k(
    const unsigned short* __restrict__ A,   // (2048,768) bf16
    const unsigned short* __restrict__ Bm,  // (512,768) bf16 (B^T layout)
    float* __restrict__ Cm)                 // (2048,512) f32
{
  __shared__ unsigned short As[BM][LDP];
  __shared__ unsigned short Bs[BN][LDP];
  const int bm = blockIdx.x, bn = blockIdx.y;
  const int tid = threadIdx.x, lane = tid & 63, wv = tid >> 6;
  const int wm = wv >> 1, wn = wv & 1;          // 2x2 wave grid

  f32x4 acc[2] = {};

  for (int k0 = 0; k0 < Hn; k0 += BK) {
    {
      const int r = tid >> 2, kc = (tid & 3) * 8;
      const unsigned short* src = A + (size_t)(bm * BM + r) * Hn + k0 + kc;
      *reinterpret_cast<ulonglong2*>(&As[r][kc]) =
          *reinterpret_cast<const ulonglong2*>(src);
    }
    if (tid < 128) {
      const int r = tid >> 2, kc = (tid & 3) * 8;
      const unsigned short* src = Bm + (size_t)(bn * BN + r) * Hn + k0 + kc;
      *reinterpret_cast<ulonglong2*>(&Bs[r][kc]) =
          *reinterpret_cast<const ulonglong2*>(src);
    }
    __syncthreads();

    const int kr = (lane >> 4) * 8, rl = lane & 15;
    const bf16x8 bf = *reinterpret_cast<const bf16x8*>(&Bs[wn * 16 + rl][kr]);
    #pragma unroll
    for (int mi = 0; mi < 2; ++mi) {
      const bf16x8 af =
          *reinterpret_cast<const bf16x8*>(&As[wm * 32 + mi * 16 + rl][kr]);
      acc[mi] = __builtin_amdgcn_mfma_f32_16x16x32_bf16(af, bf, acc[mi], 0, 0, 0);
    }
    __syncthreads();
  }

  const int cl = lane & 15, rg = (lane >> 4) * 4;
  const int col = bn * BN + wn * 16 + cl;
  #pragma unroll
  for (int mi = 0; mi < 2; ++mi) {
    #pragma unroll
    for (int r = 0; r < 4; ++r) {
      const int row = bm * BM + wm * 32 + mi * 16 + rg + r;
      Cm[(size_t)row * NP + col] = acc[mi][r];
    }
  }
}

// ---------------------------------------------------------------------------
// Kernel 3: CE per entity (one wave each; 4 waves/block). Bias added here.
// ---------------------------------------------------------------------------
__global__ __launch_bounds__(256) void ce_k(
    const float* __restrict__ logits,        // (2048,512)
    const float* __restrict__ bv,            // (457)
    const int* __restrict__ attr,            // (B,E)
    const unsigned char* __restrict__ emask, // (B,E)
    float* __restrict__ nll)                 // (2048)
{
  const int wv = threadIdx.x >> 6, lane = threadIdx.x & 63;
  const int be = blockIdx.x * 4 + wv;
  if (!emask[be]) { if (lane == 0) nll[be] = 0.f; return; }
  const float* row = logits + (size_t)be * NP;

  float mx = -3.4e38f;
  for (int i = lane; i < Cn; i += 64) mx = fmaxf(mx, row[i] + bv[i]);
  #pragma unroll
  for (int o = 32; o; o >>= 1) mx = fmaxf(mx, __shfl_xor(mx, o, 64));
  float sm = 0.f;
  for (int i = lane; i < Cn; i += 64) sm += __expf(row[i] + bv[i] - mx);
  #pragma unroll
  for (int o = 32; o; o >>= 1) sm += __shfl_xor(sm, o, 64);
  if (lane == 0) {
    const int tg = attr[be];
    nll[be] = mx + logf(sm) - (row[tg] + bv[tg]);
  }
}

// ---------------------------------------------------------------------------
// Kernel 4: deterministic final reduction.
// ---------------------------------------------------------------------------
__global__ __launch_bounds__(256) void reduce_k(
    const float* __restrict__ nll,
    const unsigned char* __restrict__ emask,
    float* __restrict__ out)
{
  const int tid = threadIdx.x;
  float s = 0.f, c = 0.f;
  for (int i = tid; i < Bn * En; i += 256) {
    s += nll[i];
    c += (float)emask[i];
  }
  #pragma unroll
  for (int o = 32; o; o >>= 1) {
    s += __shfl_xor(s, o, 64);
    c += __shfl_xor(c, o, 64);
  }
  __shared__ float ws_[4], wc_[4];
  const int wave = tid >> 6, lane = tid & 63;
  if (lane == 0) { ws_[wave] = s; wc_[wave] = c; }
  __syncthreads();
  if (tid == 0) {
    out[0] = (ws_[0] + ws_[1] + ws_[2] + ws_[3]) /
             (wc_[0] + wc_[1] + wc_[2] + wc_[3]);
  }
}

// ---------------------------------------------------------------------------
extern "C" void kernel_launch(void* const* d_in, const int* in_sizes, int n_in,
                              void* d_out, int out_size, void* d_ws, size_t ws_size,
                              hipStream_t stream) {
  const float* hidden        = (const float*)d_in[0];
  const int* attr            = (const int*)d_in[3];
  const int* el              = (const int*)d_in[4];
  const int* elen            = (const int*)d_in[5];
  const unsigned char* emask = (const unsigned char*)d_in[6];
  const float* Wm            = (const float*)d_in[7];
  const float* bv            = (const float*)d_in[8];

  unsigned short* entbf = (unsigned short*)d_ws;            // 2048*768 bf16
  unsigned short* wbf   = entbf + (size_t)Bn * En * Hn;     // 512*768 bf16
  float* logits = (float*)(wbf + (size_t)NP * Hn);          // 2048*512 f32
  float* nll    = logits + (size_t)Bn * En * NP;            // 2048 f32
  unsigned int* pk2buf = (unsigned int*)(nll + Bn * En);    // B*4*S u32
  unsigned short* entp =
      (unsigned short*)(pk2buf + (size_t)Bn * 4 * Sn);      // SCH*2048*768 bf16

  hipLaunchKernelGGL(pack_k, dim3(1024), dim3(256), 0, stream, el, pk2buf);
  hipLaunchKernelGGL(pool_k, dim3(Bn, Hn / PBN, SCH), dim3(256), 0, stream,
                     hidden, pk2buf, entp);
  hipLaunchKernelGGL(fincast_k, dim3(Bn * En + NP), dim3(384), 0, stream,
                     entp, elen, Wm, entbf, wbf);
  hipLaunchKernelGGL(gemm_k, dim3(Bn * En / BM, NP / BN), dim3(256), 0, stream,
                     entbf, wbf, logits);
  hipLaunchKernelGGL(ce_k, dim3(Bn * En / 4), dim3(256), 0, stream,
                     logits, bv, attr, emask, nll);
  hipLaunchKernelGGL(reduce_k, dim3(1), dim3(256), 0, stream,
                     nll, emask, (float*)d_out);
}